// Round 6
// baseline (394.974 us; speedup 1.0000x reference)
//
#include <hip/hip_runtime.h>
#include <stdint.h>

#define BATCH 128
#define SEQL  512
#define FDIM  768
#define CTAGS 52
#define START_IDX 50
#define STOP_IDX  51
#define NEG_INF (-3.0e38f)

// ---------------------------------------------------------------------------
// K0: transpose W [52][768] -> WT [768][52]. Tiny, runs once.
// ---------------------------------------------------------------------------
__global__ __launch_bounds__(256) void wtrans(
    const float* __restrict__ W, float* __restrict__ WT)
{
    int idx = blockIdx.x * 256 + threadIdx.x;
    if (idx < FDIM * CTAGS) {
        int k = idx / CTAGS;
        int c = idx - k * CTAGS;
        WT[idx] = W[(size_t)c * FDIM + k];
    }
}

// ---------------------------------------------------------------------------
// K1: emission GEMM (unchanged from R5 — W scalar path, F via LDS).
// ---------------------------------------------------------------------------
#define BK32 32
#define LPAD 33

__global__ __launch_bounds__(256) void emit_gemm4(
    const float* __restrict__ F, const float* __restrict__ WT,
    const float* __restrict__ bias, float* __restrict__ emit)
{
    __shared__ float buf[2][64 * LPAD];

    const int tid  = threadIdx.x;
    const int lane = tid & 63;
    const int cg   = __builtin_amdgcn_readfirstlane(tid >> 6);
    const int c0   = cg * 13;
    const int row0 = blockIdx.x * 64;

    const int r0 = tid >> 3;
    const int s0 = tid & 7;
    const float* g0 = F + (size_t)(row0 + r0) * FDIM + s0 * 4;
    const float* g1 = g0 + (size_t)32 * FDIM;
    const int i0 = r0 * LPAD + s0 * 4;
    const int i1 = (r0 + 32) * LPAD + s0 * 4;

    float acc[13];
#pragma unroll
    for (int c = 0; c < 13; ++c) acc[c] = bias[c0 + c];

    {
        float4 a0 = *(const float4*)g0;
        float4 a1 = *(const float4*)g1;
        buf[0][i0 + 0] = a0.x; buf[0][i0 + 1] = a0.y;
        buf[0][i0 + 2] = a0.z; buf[0][i0 + 3] = a0.w;
        buf[0][i1 + 0] = a1.x; buf[0][i1 + 1] = a1.y;
        buf[0][i1 + 2] = a1.z; buf[0][i1 + 3] = a1.w;
    }
    __syncthreads();

    int cur = 0;
    for (int t = 0; t < FDIM / BK32; ++t) {
        const int k0 = t * BK32;

        float4 b0, b1;
        if (t < FDIM / BK32 - 1) {
            b0 = *(const float4*)(g0 + k0 + BK32);
            b1 = *(const float4*)(g1 + k0 + BK32);
        }

        const float* fb = &buf[cur][lane * LPAD];
#pragma unroll
        for (int kk = 0; kk < BK32; kk += 4) {
            float f0 = fb[kk + 0], f1 = fb[kk + 1];
            float f2 = fb[kk + 2], f3 = fb[kk + 3];
            const float* w0 = WT + (size_t)(k0 + kk + 0) * CTAGS + c0;
            const float* w1 = WT + (size_t)(k0 + kk + 1) * CTAGS + c0;
            const float* w2 = WT + (size_t)(k0 + kk + 2) * CTAGS + c0;
            const float* w3 = WT + (size_t)(k0 + kk + 3) * CTAGS + c0;
#pragma unroll
            for (int c = 0; c < 13; ++c) {
                acc[c] = fmaf(f0, w0[c], acc[c]);
                acc[c] = fmaf(f1, w1[c], acc[c]);
                acc[c] = fmaf(f2, w2[c], acc[c]);
                acc[c] = fmaf(f3, w3[c], acc[c]);
            }
        }

        if (t < FDIM / BK32 - 1) {
            buf[cur ^ 1][i0 + 0] = b0.x; buf[cur ^ 1][i0 + 1] = b0.y;
            buf[cur ^ 1][i0 + 2] = b0.z; buf[cur ^ 1][i0 + 3] = b0.w;
            buf[cur ^ 1][i1 + 0] = b1.x; buf[cur ^ 1][i1 + 1] = b1.y;
            buf[cur ^ 1][i1 + 2] = b1.z; buf[cur ^ 1][i1 + 3] = b1.w;
        }
        __syncthreads();
        cur ^= 1;
    }

    float* eo = emit + (size_t)(row0 + lane) * CTAGS + c0;
#pragma unroll
    for (int c = 0; c < 13; ++c) eo[c] = acc[c];
}

// ---------------------------------------------------------------------------
// K2: serial Viterbi scan, v3.
//  - T-row forced into 13 named float4 registers (R5's VGPR=40 showed the
//    indexed Trow[52] was demoted to memory -> ~50 reloads/step).
//  - Emissions staged through LDS in 32-step chunks, double buffered:
//    global->reg loads for chunk c+1 issued at the START of chunk c
//    (~10k cycles of cover), reg->LDS at chunk end. In-loop e via ds_read
//    with one-step prefetch. Single-wave block -> LDS is program-ordered,
//    ZERO barriers.
//  - Masks staged to LDS once.
// ---------------------------------------------------------------------------
#define CHUNK 32
#define CQ   (CHUNK * CTAGS / 4)   // float4s per chunk = 416

__global__ __launch_bounds__(64) void viterbi_scan(
    const float* __restrict__ emit, const int* __restrict__ masks,
    const float* __restrict__ T, float* __restrict__ s_hist,
    float* __restrict__ out, int* __restrict__ btag)
{
    const int b  = blockIdx.x;
    const int to = threadIdx.x;
    const int toc = (to < CTAGS) ? to : (CTAGS - 1);

    __shared__ float ebuf[2][CHUNK * CTAGS];  // 2 x 6656 B
    __shared__ int   ml[SEQL];                // 2 KB

    // T row: 13 named float4 regs (row byte offset toc*208, 16B-aligned)
    const float4* Tq = (const float4*)(T + (size_t)toc * CTAGS);
    const float4 tr0 = Tq[0],  tr1 = Tq[1],  tr2 = Tq[2],  tr3 = Tq[3];
    const float4 tr4 = Tq[4],  tr5 = Tq[5],  tr6 = Tq[6],  tr7 = Tq[7];
    const float4 tr8 = Tq[8],  tr9 = Tq[9],  tr10 = Tq[10], tr11 = Tq[11];
    const float4 tr12 = Tq[12];
    const float tstop = T[STOP_IDX * CTAGS + toc];

    const float*  eb  = emit   + (size_t)b * SEQL * CTAGS;
    const float4* ebq = (const float4*)eb;
    const int*    mb  = masks  + (size_t)b * SEQL;
    float*        sb  = s_hist + (size_t)b * SEQL * CTAGS;

    // prologue: masks -> LDS ; chunk 0 -> LDS
#pragma unroll
    for (int j = 0; j < 8; ++j) ml[to + 64 * j] = mb[to + 64 * j];
#pragma unroll
    for (int j = 0; j < 7; ++j) {
        int idx = to + 64 * j;
        if (idx < CQ) *(float4*)&ebuf[0][idx * 4] = ebq[idx];
    }

    float cur   = (to == START_IDX) ? 0.f : -10000.f;
    float e_cur = ebuf[0][toc];          // ds ops in-order within the wave
    int   m_cur = ml[0];
    int   cb    = 0;

    for (int c = 0; c < SEQL / CHUNK; ++c) {
        // issue next chunk's global loads NOW (consumed ~10k cycles later)
        float4 st0, st1, st2, st3, st4, st5, st6;
        const int more = (c < SEQL / CHUNK - 1);
        if (more) {
            const float4* src = ebq + (size_t)(c + 1) * CQ;
            st0 = src[to];
            st1 = src[to + 64];
            st2 = src[to + 128];
            st3 = src[to + 192];
            st4 = src[to + 256];
            st5 = src[to + 320];
            if (to < CQ - 384) st6 = src[to + 384];
        }

        for (int s = 0; s < CHUNK; ++s) {
            const int t = c * CHUNK + s;

            float e_nxt = 0.f;
            if (s < CHUNK - 1) e_nxt = ebuf[cb][(s + 1) * CTAGS + toc];
            int m_nxt = (t + 1 < SEQL) ? ml[t + 1] : 0;

            if (to < CTAGS) sb[(size_t)t * CTAGS + to] = cur;

            // broadcast state (uniform -> SGPR) and add T-row
            const unsigned cu = __float_as_uint(cur);
            float a[CTAGS];
#define BCQ(q, trq)                                                          \
            a[4*q+0] = __uint_as_float(__builtin_amdgcn_readlane((int)cu, 4*q+0)) + trq.x; \
            a[4*q+1] = __uint_as_float(__builtin_amdgcn_readlane((int)cu, 4*q+1)) + trq.y; \
            a[4*q+2] = __uint_as_float(__builtin_amdgcn_readlane((int)cu, 4*q+2)) + trq.z; \
            a[4*q+3] = __uint_as_float(__builtin_amdgcn_readlane((int)cu, 4*q+3)) + trq.w;
            BCQ(0, tr0)  BCQ(1, tr1)  BCQ(2, tr2)  BCQ(3, tr3)
            BCQ(4, tr4)  BCQ(5, tr5)  BCQ(6, tr6)  BCQ(7, tr7)
            BCQ(8, tr8)  BCQ(9, tr9)  BCQ(10, tr10) BCQ(11, tr11)
            BCQ(12, tr12)
#undef BCQ

            float l1[17];
#pragma unroll
            for (int i = 0; i < 17; ++i)
                l1[i] = fmaxf(fmaxf(a[3 * i], a[3 * i + 1]), a[3 * i + 2]);
            float l2[6];
#pragma unroll
            for (int i = 0; i < 5; ++i)
                l2[i] = fmaxf(fmaxf(l1[3 * i], l1[3 * i + 1]), l1[3 * i + 2]);
            l2[5] = fmaxf(fmaxf(l1[15], l1[16]), a[51]);
            const float m = fmaxf(fmaxf(fmaxf(l2[0], l2[1]), l2[2]),
                                  fmaxf(fmaxf(l2[3], l2[4]), l2[5]));

            cur   = m_cur ? (m + e_cur) : cur;
            e_cur = e_nxt;
            m_cur = m_nxt;
        }

        // write next chunk to the other buffer; then read its first emission
        if (more) {
            const int nb = cb ^ 1;
            *(float4*)&ebuf[nb][to * 4]         = st0;
            *(float4*)&ebuf[nb][(to + 64) * 4]  = st1;
            *(float4*)&ebuf[nb][(to + 128) * 4] = st2;
            *(float4*)&ebuf[nb][(to + 192) * 4] = st3;
            *(float4*)&ebuf[nb][(to + 256) * 4] = st4;
            *(float4*)&ebuf[nb][(to + 320) * 4] = st5;
            if (to < CQ - 384) *(float4*)&ebuf[nb][(to + 384) * 4] = st6;
            e_cur = ebuf[nb][toc];   // in-order LDS: write completes first
        }
        cb ^= 1;
    }

    // final scores + wave argmax (first-index tiebreak)
    float v   = (to < CTAGS) ? (cur + tstop) : NEG_INF;
    int  bidx = to;
#pragma unroll
    for (int s = 1; s < 64; s <<= 1) {
        float ov = __shfl_xor(v, s);
        int   oi = __shfl_xor(bidx, s);
        if (ov > v || (ov == v && oi < bidx)) { v = ov; bidx = oi; }
    }
    if (to == 0) { out[b] = v; btag[b] = bidx; }
}

// ---------------------------------------------------------------------------
// K3: backpointers, parallel over (b,t). (unchanged, known-good)
// ---------------------------------------------------------------------------
#define PPW 16

__global__ __launch_bounds__(256) void bp_compute(
    const float* __restrict__ s_hist, const float* __restrict__ T,
    unsigned char* __restrict__ bp)
{
    const int lane = threadIdx.x & 63;
    const int wv   = __builtin_amdgcn_readfirstlane(threadIdx.x >> 6);
    const int toc  = (lane < CTAGS) ? lane : (CTAGS - 1);
    const int w    = blockIdx.x * 4 + wv;

    float Trow[CTAGS];
#pragma unroll
    for (int f = 0; f < CTAGS; ++f) Trow[f] = T[toc * CTAGS + f];

    for (int i = 0; i < PPW; ++i) {
        const int p = w * PPW + i;            // p = b*SEQL + t
        const float* sp = s_hist + (size_t)p * CTAGS;

        float a[CTAGS];
#pragma unroll
        for (int q = 0; q < 13; ++q) {
            float4 sv = *(const float4*)(sp + q * 4);
            a[q * 4 + 0] = sv.x + Trow[q * 4 + 0];
            a[q * 4 + 1] = sv.y + Trow[q * 4 + 1];
            a[q * 4 + 2] = sv.z + Trow[q * 4 + 2];
            a[q * 4 + 3] = sv.w + Trow[q * 4 + 3];
        }

        float l1[17];
#pragma unroll
        for (int j = 0; j < 17; ++j)
            l1[j] = fmaxf(fmaxf(a[3 * j], a[3 * j + 1]), a[3 * j + 2]);
        float l2[6];
#pragma unroll
        for (int j = 0; j < 5; ++j)
            l2[j] = fmaxf(fmaxf(l1[3 * j], l1[3 * j + 1]), l1[3 * j + 2]);
        l2[5] = fmaxf(fmaxf(l1[15], l1[16]), a[51]);
        const float m = fmaxf(fmaxf(fmaxf(l2[0], l2[1]), l2[2]),
                              fmaxf(fmaxf(l2[3], l2[4]), l2[5]));

        int c1[18];
#pragma unroll
        for (int j = 0; j < 17; ++j) {
            int x = (a[3 * j]     == m) ? (3 * j)     : 63;
            int y = (a[3 * j + 1] == m) ? (3 * j + 1) : 63;
            int z = (a[3 * j + 2] == m) ? (3 * j + 2) : 63;
            c1[j] = min(min(x, y), z);
        }
        c1[17] = (a[51] == m) ? 51 : 63;
        int c2[6];
#pragma unroll
        for (int j = 0; j < 6; ++j)
            c2[j] = min(min(c1[3 * j], c1[3 * j + 1]), c1[3 * j + 2]);
        const int idx = min(min(min(c2[0], c2[1]), c2[2]),
                            min(min(c2[3], c2[4]), c2[5]));

        if (lane < CTAGS)
            bp[(size_t)p * CTAGS + lane] = (unsigned char)idx;
    }
}

// ---------------------------------------------------------------------------
// K4: backtrack (unchanged, known-good).
// ---------------------------------------------------------------------------
__global__ __launch_bounds__(64) void viterbi_bt(
    const unsigned char* __restrict__ bp, const int* __restrict__ masks,
    const int* __restrict__ btag, float* __restrict__ out)
{
    const int b   = blockIdx.x;
    const int tid = threadIdx.x;

    __shared__ __align__(16) unsigned char bpl[SEQL * CTAGS];
    __shared__ int ml[SEQL];
    __shared__ unsigned char pathb[SEQL];

    const uint4* src = (const uint4*)(bp + (size_t)b * SEQL * CTAGS);
    for (int i = tid; i < SEQL * CTAGS / 16; i += 64)
        ((uint4*)bpl)[i] = src[i];
    for (int i = tid; i < SEQL; i += 64) ml[i] = masks[(size_t)b * SEQL + i];
    __syncthreads();

    int c = btag[b];
    if (tid == 0) pathb[SEQL - 1] = (unsigned char)c;
    for (int i = SEQL - 2; i >= 0; --i) {
        int nxt = bpl[(i + 1) * CTAGS + c];
        c = ml[i] ? nxt : c;
        if (tid == 0) pathb[i] = (unsigned char)c;
    }
    __syncthreads();

    float* po = out + BATCH + (size_t)b * SEQL;
#pragma unroll
    for (int i = 0; i < 8; ++i)
        po[i * 64 + tid] = (float)pathb[i * 64 + tid];
}

// ---------------------------------------------------------------------------
extern "C" void kernel_launch(void* const* d_in, const int* in_sizes, int n_in,
                              void* d_out, int out_size, void* d_ws, size_t ws_size,
                              hipStream_t stream)
{
    const float* features = (const float*)d_in[0];
    const int*   masks    = (const int*)d_in[1];
    const float* W        = (const float*)d_in[2];
    const float* bias     = (const float*)d_in[3];
    const float* T        = (const float*)d_in[4];

    float* out = (float*)d_out;

    const size_t emit_bytes = (size_t)BATCH * SEQL * CTAGS * sizeof(float);
    const size_t bp_bytes   = (size_t)BATCH * SEQL * CTAGS;
    float*         emit   = (float*)d_ws;
    float*         s_hist = emit;  // alias: scan consumes emit[t] before overwrite
    unsigned char* bpws   = (unsigned char*)d_ws + emit_bytes;
    float*         WT     = (float*)bpws;  // dead before bp_compute writes
    int*           btag   = (int*)((unsigned char*)d_ws + emit_bytes + bp_bytes);

    wtrans<<<(FDIM * CTAGS + 255) / 256, 256, 0, stream>>>(W, WT);
    emit_gemm4<<<BATCH * SEQL / 64, 256, 0, stream>>>(features, WT, bias, emit);
    viterbi_scan<<<BATCH, 64, 0, stream>>>(emit, masks, T, s_hist, out, btag);
    bp_compute<<<BATCH * SEQL / (4 * PPW), 256, 0, stream>>>(s_hist, T, bpws);
    viterbi_bt<<<BATCH, 64, 0, stream>>>(bpws, masks, btag, out);
}

// Round 7
// 309.856 us; speedup vs baseline: 1.2747x; 1.2747x over previous
//
#include <hip/hip_runtime.h>
#include <stdint.h>

#define BATCH 128
#define SEQL  512
#define FDIM  768
#define CTAGS 52
#define START_IDX 50
#define STOP_IDX  51
#define NEG_INF (-3.0e38f)

// ---------------------------------------------------------------------------
// K0: transpose W [52][768] -> WT [768][52]. Tiny, runs once.
// ---------------------------------------------------------------------------
__global__ __launch_bounds__(256) void wtrans(
    const float* __restrict__ W, float* __restrict__ WT)
{
    int idx = blockIdx.x * 256 + threadIdx.x;
    if (idx < FDIM * CTAGS) {
        int k = idx / CTAGS;
        int c = idx - k * CTAGS;
        WT[idx] = W[(size_t)c * FDIM + k];
    }
}

// ---------------------------------------------------------------------------
// K1: emission GEMM (unchanged — W scalar path, F via LDS).
// ---------------------------------------------------------------------------
#define BK32 32
#define LPAD 33

__global__ __launch_bounds__(256) void emit_gemm4(
    const float* __restrict__ F, const float* __restrict__ WT,
    const float* __restrict__ bias, float* __restrict__ emit)
{
    __shared__ float buf[2][64 * LPAD];

    const int tid  = threadIdx.x;
    const int lane = tid & 63;
    const int cg   = __builtin_amdgcn_readfirstlane(tid >> 6);
    const int c0   = cg * 13;
    const int row0 = blockIdx.x * 64;

    const int r0 = tid >> 3;
    const int s0 = tid & 7;
    const float* g0 = F + (size_t)(row0 + r0) * FDIM + s0 * 4;
    const float* g1 = g0 + (size_t)32 * FDIM;
    const int i0 = r0 * LPAD + s0 * 4;
    const int i1 = (r0 + 32) * LPAD + s0 * 4;

    float acc[13];
#pragma unroll
    for (int c = 0; c < 13; ++c) acc[c] = bias[c0 + c];

    {
        float4 a0 = *(const float4*)g0;
        float4 a1 = *(const float4*)g1;
        buf[0][i0 + 0] = a0.x; buf[0][i0 + 1] = a0.y;
        buf[0][i0 + 2] = a0.z; buf[0][i0 + 3] = a0.w;
        buf[0][i1 + 0] = a1.x; buf[0][i1 + 1] = a1.y;
        buf[0][i1 + 2] = a1.z; buf[0][i1 + 3] = a1.w;
    }
    __syncthreads();

    int cur = 0;
    for (int t = 0; t < FDIM / BK32; ++t) {
        const int k0 = t * BK32;

        float4 b0, b1;
        if (t < FDIM / BK32 - 1) {
            b0 = *(const float4*)(g0 + k0 + BK32);
            b1 = *(const float4*)(g1 + k0 + BK32);
        }

        const float* fb = &buf[cur][lane * LPAD];
#pragma unroll
        for (int kk = 0; kk < BK32; kk += 4) {
            float f0 = fb[kk + 0], f1 = fb[kk + 1];
            float f2 = fb[kk + 2], f3 = fb[kk + 3];
            const float* w0 = WT + (size_t)(k0 + kk + 0) * CTAGS + c0;
            const float* w1 = WT + (size_t)(k0 + kk + 1) * CTAGS + c0;
            const float* w2 = WT + (size_t)(k0 + kk + 2) * CTAGS + c0;
            const float* w3 = WT + (size_t)(k0 + kk + 3) * CTAGS + c0;
#pragma unroll
            for (int c = 0; c < 13; ++c) {
                acc[c] = fmaf(f0, w0[c], acc[c]);
                acc[c] = fmaf(f1, w1[c], acc[c]);
                acc[c] = fmaf(f2, w2[c], acc[c]);
                acc[c] = fmaf(f3, w3[c], acc[c]);
            }
        }

        if (t < FDIM / BK32 - 1) {
            buf[cur ^ 1][i0 + 0] = b0.x; buf[cur ^ 1][i0 + 1] = b0.y;
            buf[cur ^ 1][i0 + 2] = b0.z; buf[cur ^ 1][i0 + 3] = b0.w;
            buf[cur ^ 1][i1 + 0] = b1.x; buf[cur ^ 1][i1 + 1] = b1.y;
            buf[cur ^ 1][i1 + 2] = b1.z; buf[cur ^ 1][i1 + 3] = b1.w;
        }
        __syncthreads();
        cur ^= 1;
    }

    float* eo = emit + (size_t)(row0 + lane) * CTAGS + c0;
#pragma unroll
    for (int c = 0; c < 13; ++c) eo[c] = acc[c];
}

// ---------------------------------------------------------------------------
// K2: serial Viterbi scan, v4 — NO readlane. State lives in LDS (52 floats);
// broadcast via 13 uniform-address ds_read_b128 (same addr across lanes =
// HW broadcast, conflict-free). Single-wave block => LDS pipe is in-order
// => zero barriers: step t's ds_write of the new state precedes step t+1's
// ds_reads in program order. Emissions/masks staged as in R6.
// ---------------------------------------------------------------------------
#define CHUNK 32
#define CQ   (CHUNK * CTAGS / 4)   // float4s per chunk = 416

__global__ __launch_bounds__(64) void viterbi_scan(
    const float* __restrict__ emit, const int* __restrict__ masks,
    const float* __restrict__ T, float* __restrict__ s_hist,
    float* __restrict__ out, int* __restrict__ btag)
{
    const int b  = blockIdx.x;
    const int to = threadIdx.x;
    const int toc = (to < CTAGS) ? to : (CTAGS - 1);

    __shared__ float ebuf[2][CHUNK * CTAGS];     // 2 x 6656 B
    __shared__ int   ml[SEQL];                   // 2 KB
    __shared__ __align__(16) float st[64];       // state vector (52 used)

    // T row: 13 named float4 regs
    const float4* Tq = (const float4*)(T + (size_t)toc * CTAGS);
    const float4 tr0 = Tq[0],  tr1 = Tq[1],  tr2 = Tq[2],  tr3 = Tq[3];
    const float4 tr4 = Tq[4],  tr5 = Tq[5],  tr6 = Tq[6],  tr7 = Tq[7];
    const float4 tr8 = Tq[8],  tr9 = Tq[9],  tr10 = Tq[10], tr11 = Tq[11];
    const float4 tr12 = Tq[12];
    const float tstop = T[STOP_IDX * CTAGS + toc];

    const float*  eb  = emit   + (size_t)b * SEQL * CTAGS;
    const float4* ebq = (const float4*)eb;
    const int*    mb  = masks  + (size_t)b * SEQL;
    float*        sb  = s_hist + (size_t)b * SEQL * CTAGS;

    // prologue: masks -> LDS ; chunk 0 -> LDS ; init state in LDS
#pragma unroll
    for (int j = 0; j < 8; ++j) ml[to + 64 * j] = mb[to + 64 * j];
#pragma unroll
    for (int j = 0; j < 7; ++j) {
        int idx = to + 64 * j;
        if (idx < CQ) *(float4*)&ebuf[0][idx * 4] = ebq[idx];
    }
    st[to] = (to == START_IDX) ? 0.f : -10000.f;   // in-order before reads

    float cur   = (to == START_IDX) ? 0.f : -10000.f;  // lane's own state
    float e_cur = ebuf[0][toc];
    int   m_cur = ml[0];
    int   cb    = 0;

    for (int c = 0; c < SEQL / CHUNK; ++c) {
        // issue next chunk's global loads NOW (consumed ~10k cycles later)
        float4 st0, st1, st2, st3, st4, st5, st6;
        const int more = (c < SEQL / CHUNK - 1);
        if (more) {
            const float4* src = ebq + (size_t)(c + 1) * CQ;
            st0 = src[to];
            st1 = src[to + 64];
            st2 = src[to + 128];
            st3 = src[to + 192];
            st4 = src[to + 256];
            st5 = src[to + 320];
            if (to < CQ - 384) st6 = src[to + 384];
        }

        for (int s = 0; s < CHUNK; ++s) {
            const int t = c * CHUNK + s;

            float e_nxt = 0.f;
            if (s < CHUNK - 1) e_nxt = ebuf[cb][(s + 1) * CTAGS + toc];
            int m_nxt = (t + 1 < SEQL) ? ml[t + 1] : 0;

            // store pre-update state
            if (to < CTAGS) sb[(size_t)t * CTAGS + to] = cur;

            // broadcast state via uniform-address LDS quad reads
            const float4 s0q  = *(const float4*)&st[0];
            const float4 s1q  = *(const float4*)&st[4];
            const float4 s2q  = *(const float4*)&st[8];
            const float4 s3q  = *(const float4*)&st[12];
            const float4 s4q  = *(const float4*)&st[16];
            const float4 s5q  = *(const float4*)&st[20];
            const float4 s6q  = *(const float4*)&st[24];
            const float4 s7q  = *(const float4*)&st[28];
            const float4 s8q  = *(const float4*)&st[32];
            const float4 s9q  = *(const float4*)&st[36];
            const float4 s10q = *(const float4*)&st[40];
            const float4 s11q = *(const float4*)&st[44];
            const float4 s12q = *(const float4*)&st[48];

            float a[CTAGS];
#define ADQ(q, sq, trq)                                                      \
            a[4*q+0] = sq.x + trq.x;  a[4*q+1] = sq.y + trq.y;               \
            a[4*q+2] = sq.z + trq.z;  a[4*q+3] = sq.w + trq.w;
            ADQ(0, s0q, tr0)   ADQ(1, s1q, tr1)   ADQ(2, s2q, tr2)
            ADQ(3, s3q, tr3)   ADQ(4, s4q, tr4)   ADQ(5, s5q, tr5)
            ADQ(6, s6q, tr6)   ADQ(7, s7q, tr7)   ADQ(8, s8q, tr8)
            ADQ(9, s9q, tr9)   ADQ(10, s10q, tr10) ADQ(11, s11q, tr11)
            ADQ(12, s12q, tr12)
#undef ADQ

            float l1[17];
#pragma unroll
            for (int i = 0; i < 17; ++i)
                l1[i] = fmaxf(fmaxf(a[3 * i], a[3 * i + 1]), a[3 * i + 2]);
            float l2[6];
#pragma unroll
            for (int i = 0; i < 5; ++i)
                l2[i] = fmaxf(fmaxf(l1[3 * i], l1[3 * i + 1]), l1[3 * i + 2]);
            l2[5] = fmaxf(fmaxf(l1[15], l1[16]), a[51]);
            const float m = fmaxf(fmaxf(fmaxf(l2[0], l2[1]), l2[2]),
                                  fmaxf(fmaxf(l2[3], l2[4]), l2[5]));

            cur = m_cur ? (m + e_cur) : cur;

            // publish new state (read by next step's ds_reads, in-order)
            if (to < CTAGS) st[to] = cur;

            e_cur = e_nxt;
            m_cur = m_nxt;
        }

        // write next chunk to the other buffer; then read its first emission
        if (more) {
            const int nb = cb ^ 1;
            *(float4*)&ebuf[nb][to * 4]         = st0;
            *(float4*)&ebuf[nb][(to + 64) * 4]  = st1;
            *(float4*)&ebuf[nb][(to + 128) * 4] = st2;
            *(float4*)&ebuf[nb][(to + 192) * 4] = st3;
            *(float4*)&ebuf[nb][(to + 256) * 4] = st4;
            *(float4*)&ebuf[nb][(to + 320) * 4] = st5;
            if (to < CQ - 384) *(float4*)&ebuf[nb][(to + 384) * 4] = st6;
            e_cur = ebuf[nb][toc];   // in-order LDS: writes complete first
        }
        cb ^= 1;
    }

    // final scores + wave argmax (first-index tiebreak)
    float v   = (to < CTAGS) ? (cur + tstop) : NEG_INF;
    int  bidx = to;
#pragma unroll
    for (int s = 1; s < 64; s <<= 1) {
        float ov = __shfl_xor(v, s);
        int   oi = __shfl_xor(bidx, s);
        if (ov > v || (ov == v && oi < bidx)) { v = ov; bidx = oi; }
    }
    if (to == 0) { out[b] = v; btag[b] = bidx; }
}

// ---------------------------------------------------------------------------
// K3: backpointers, parallel over (b,t). (unchanged, known-good)
// ---------------------------------------------------------------------------
#define PPW 16

__global__ __launch_bounds__(256) void bp_compute(
    const float* __restrict__ s_hist, const float* __restrict__ T,
    unsigned char* __restrict__ bp)
{
    const int lane = threadIdx.x & 63;
    const int wv   = __builtin_amdgcn_readfirstlane(threadIdx.x >> 6);
    const int toc  = (lane < CTAGS) ? lane : (CTAGS - 1);
    const int w    = blockIdx.x * 4 + wv;

    float Trow[CTAGS];
#pragma unroll
    for (int f = 0; f < CTAGS; ++f) Trow[f] = T[toc * CTAGS + f];

    for (int i = 0; i < PPW; ++i) {
        const int p = w * PPW + i;            // p = b*SEQL + t
        const float* sp = s_hist + (size_t)p * CTAGS;

        float a[CTAGS];
#pragma unroll
        for (int q = 0; q < 13; ++q) {
            float4 sv = *(const float4*)(sp + q * 4);
            a[q * 4 + 0] = sv.x + Trow[q * 4 + 0];
            a[q * 4 + 1] = sv.y + Trow[q * 4 + 1];
            a[q * 4 + 2] = sv.z + Trow[q * 4 + 2];
            a[q * 4 + 3] = sv.w + Trow[q * 4 + 3];
        }

        float l1[17];
#pragma unroll
        for (int j = 0; j < 17; ++j)
            l1[j] = fmaxf(fmaxf(a[3 * j], a[3 * j + 1]), a[3 * j + 2]);
        float l2[6];
#pragma unroll
        for (int j = 0; j < 5; ++j)
            l2[j] = fmaxf(fmaxf(l1[3 * j], l1[3 * j + 1]), l1[3 * j + 2]);
        l2[5] = fmaxf(fmaxf(l1[15], l1[16]), a[51]);
        const float m = fmaxf(fmaxf(fmaxf(l2[0], l2[1]), l2[2]),
                              fmaxf(fmaxf(l2[3], l2[4]), l2[5]));

        int c1[18];
#pragma unroll
        for (int j = 0; j < 17; ++j) {
            int x = (a[3 * j]     == m) ? (3 * j)     : 63;
            int y = (a[3 * j + 1] == m) ? (3 * j + 1) : 63;
            int z = (a[3 * j + 2] == m) ? (3 * j + 2) : 63;
            c1[j] = min(min(x, y), z);
        }
        c1[17] = (a[51] == m) ? 51 : 63;
        int c2[6];
#pragma unroll
        for (int j = 0; j < 6; ++j)
            c2[j] = min(min(c1[3 * j], c1[3 * j + 1]), c1[3 * j + 2]);
        const int idx = min(min(min(c2[0], c2[1]), c2[2]),
                            min(min(c2[3], c2[4]), c2[5]));

        if (lane < CTAGS)
            bp[(size_t)p * CTAGS + lane] = (unsigned char)idx;
    }
}

// ---------------------------------------------------------------------------
// K4: backtrack (unchanged, known-good).
// ---------------------------------------------------------------------------
__global__ __launch_bounds__(64) void viterbi_bt(
    const unsigned char* __restrict__ bp, const int* __restrict__ masks,
    const int* __restrict__ btag, float* __restrict__ out)
{
    const int b   = blockIdx.x;
    const int tid = threadIdx.x;

    __shared__ __align__(16) unsigned char bpl[SEQL * CTAGS];
    __shared__ int ml[SEQL];
    __shared__ unsigned char pathb[SEQL];

    const uint4* src = (const uint4*)(bp + (size_t)b * SEQL * CTAGS);
    for (int i = tid; i < SEQL * CTAGS / 16; i += 64)
        ((uint4*)bpl)[i] = src[i];
    for (int i = tid; i < SEQL; i += 64) ml[i] = masks[(size_t)b * SEQL + i];
    __syncthreads();

    int c = btag[b];
    if (tid == 0) pathb[SEQL - 1] = (unsigned char)c;
    for (int i = SEQL - 2; i >= 0; --i) {
        int nxt = bpl[(i + 1) * CTAGS + c];
        c = ml[i] ? nxt : c;
        if (tid == 0) pathb[i] = (unsigned char)c;
    }
    __syncthreads();

    float* po = out + BATCH + (size_t)b * SEQL;
#pragma unroll
    for (int i = 0; i < 8; ++i)
        po[i * 64 + tid] = (float)pathb[i * 64 + tid];
}

// ---------------------------------------------------------------------------
extern "C" void kernel_launch(void* const* d_in, const int* in_sizes, int n_in,
                              void* d_out, int out_size, void* d_ws, size_t ws_size,
                              hipStream_t stream)
{
    const float* features = (const float*)d_in[0];
    const int*   masks    = (const int*)d_in[1];
    const float* W        = (const float*)d_in[2];
    const float* bias     = (const float*)d_in[3];
    const float* T        = (const float*)d_in[4];

    float* out = (float*)d_out;

    const size_t emit_bytes = (size_t)BATCH * SEQL * CTAGS * sizeof(float);
    const size_t bp_bytes   = (size_t)BATCH * SEQL * CTAGS;
    float*         emit   = (float*)d_ws;
    float*         s_hist = emit;  // alias: scan consumes emit[t] before overwrite
    unsigned char* bpws   = (unsigned char*)d_ws + emit_bytes;
    float*         WT     = (float*)bpws;  // dead before bp_compute writes
    int*           btag   = (int*)((unsigned char*)d_ws + emit_bytes + bp_bytes);

    wtrans<<<(FDIM * CTAGS + 255) / 256, 256, 0, stream>>>(W, WT);
    emit_gemm4<<<BATCH * SEQL / 64, 256, 0, stream>>>(features, WT, bias, emit);
    viterbi_scan<<<BATCH, 64, 0, stream>>>(emit, masks, T, s_hist, out, btag);
    bp_compute<<<BATCH * SEQL / (4 * PPW), 256, 0, stream>>>(s_hist, T, bpws);
    viterbi_bt<<<BATCH, 64, 0, stream>>>(bpws, masks, btag, out);
}